// Round 19
// baseline (165.018 us; speedup 1.0000x reference)
//
#include <hip/hip_runtime.h>
#include <hip/hip_bf16.h>

// QDense: out = s * (U X U^H)[:128,:128] / tr + (1-s) * diag(softmax(rand_w))
// B=512, D=256, O=128.
// Round-19 = round-17 (149us best) with U moved OUT of LDS:
//   - U fragment-packed in GLOBAL (L1/L2-hot; each load = wave-uniform base
//     + lane*8 shorts = perfectly coalesced 1KB).  1-step register ring
//     (uhr/uhi, 8 VGPRs): CONS(ks) consumes held frag, prefetches (ks+1)&7
//     (addresses pair-invariant -> ring always primed).
//   - LDS = X-ring 64KB + Yt 16KB = 80KB exactly -> 2 blocks/CU (was 1):
//     4 waves/SIMD of TLP to hide the barrier-phase latency.
// Everything else r17: full-row 1KB coalesced X loads, f32->bf16 at staging,
// 2 pair-slot X ring, slice-granular 16-reg held H, XCD sibling pairing,
// packed-U stage B, TRDOT trace on staging regs, 1 barrier/pair + lgkmcnt.
// 1024 blocks, 512 thr.

typedef __attribute__((ext_vector_type(4))) float f32x4;
typedef __attribute__((ext_vector_type(8))) short bf16x8;

static __device__ __forceinline__ short f2bf(float f) {   // prep kernels only
    unsigned u = __float_as_uint(f);
    u += 0x7fffu + ((u >> 16) & 1u);
    return (short)(u >> 16);
}

static __device__ __forceinline__ float b2f(unsigned short h) {
    return __uint_as_float(((unsigned)h) << 16);
}

static __device__ __forceinline__ unsigned cvtpk2(float lo, float hi) {
    union { __hip_bfloat162 h; unsigned u; } c;
    c.h = __float22bfloat162_rn(float2{lo, hi});
    return c.u;
}

static __device__ __forceinline__ uint2 cvt2(f32x4 v) {
    uint2 r;
    r.x = cvtpk2(v[0], v[1]);
    r.y = cvtpk2(v[2], v[3]);
    return r;
}

static __device__ __forceinline__ f32x4 mfma16(bf16x8 a, bf16x8 b, f32x4 c) {
    return __builtin_amdgcn_mfma_f32_16x16x32_bf16(a, b, c, 0, 0, 0);
}

// ---- prep: U -> bf16 fragment-packed (Upr/Upi) ----
__global__ void qprep_u(const float* __restrict__ wt,
                        short* __restrict__ Upr, short* __restrict__ Upi) {
    int idx = blockIdx.x * 256 + threadIdx.x;     // j*256+k, j<128
    int j = idx >> 8, k = idx & 255;
    float2 v = ((const float2*)wt)[idx];
    int g = j >> 4, s = k >> 5;
    int lanep = (j & 15) | (((k >> 3) & 3) << 4);
    int p = ((g * 8 + s) * 64 + lanep) * 8 + (k & 7);
    Upr[p] = f2bf(v.x);
    Upi[p] = f2bf(v.y);
}

__global__ void qprep_ps(const float* __restrict__ rw, const float* __restrict__ lm,
                         float* __restrict__ pv, float* __restrict__ sv) {
    int t = threadIdx.x;
    float w0 = rw[t], w1 = rw[t + 64];
    float m = fmaxf(w0, w1);
    #pragma unroll
    for (int o = 32; o > 0; o >>= 1) m = fmaxf(m, __shfl_xor(m, o));
    float e0 = expf(w0 - m), e1 = expf(w1 - m);
    float ss = e0 + e1;
    #pragma unroll
    for (int o = 32; o > 0; o >>= 1) ss += __shfl_xor(ss, o);
    pv[t] = e0 / ss;
    pv[t + 64] = e1 / ss;
    if (t == 0) sv[0] = 1.f / (1.f + expf(-lm[0]));
}

// Q[j][k] = P[k][j], P = U_sub^H U_sub  (bf16, row-major)
__global__ void qprep_q(const float* __restrict__ wt,
                        short* __restrict__ Qrb, short* __restrict__ Qib) {
    int j = blockIdx.x;
    int k = threadIdx.x;
    float ar = 0.f, ai = 0.f;
    for (int i = 0; i < 128; ++i) {
        float2 uk = ((const float2*)wt)[i * 256 + k];
        float2 uj = ((const float2*)wt)[i * 256 + j];
        ar += uk.x * uj.x + uk.y * uj.y;
        ai += uk.x * uj.y - uk.y * uj.x;
    }
    Qrb[j * 256 + k] = f2bf(ar);
    Qib[j * 256 + k] = f2bf(ai);
}

#define PB(Q) ((Q) * 32)                 // pair row base (rows in batch)

// ---- trace dot, direct Q loads (r17-proven) ----
#define TRDOT(RB, A0, A1, A2, A3) do {                                          \
    const int qo0 = ((RB) + sr0) * 256 + xl4;                                   \
    const int qo1 = ((RB) + sr1) * 256 + xl4;                                   \
    ushort4 hr0 = *(const ushort4*)(Qrb + qo0);                                 \
    ushort4 hr1 = *(const ushort4*)(Qrb + qo1);                                 \
    ushort4 hi0 = *(const ushort4*)(Qib + qo0);                                 \
    ushort4 hi1 = *(const ushort4*)(Qib + qo1);                                 \
    tracc += A0[0]*b2f(hr0.x) + A0[1]*b2f(hr0.y)                                \
           + A0[2]*b2f(hr0.z) + A0[3]*b2f(hr0.w);                               \
    tracc += A1[0]*b2f(hr1.x) + A1[1]*b2f(hr1.y)                                \
           + A1[2]*b2f(hr1.z) + A1[3]*b2f(hr1.w);                               \
    tracc -= A2[0]*b2f(hi0.x) + A2[1]*b2f(hi0.y)                                \
           + A2[2]*b2f(hi0.z) + A2[3]*b2f(hi0.w);                               \
    tracc -= A3[0]*b2f(hi1.x) + A3[1]*b2f(hi1.y)                                \
           + A3[2]*b2f(hi1.z) + A3[3]*b2f(hi1.w);                               \
} while (0)

// ---- consume one ks step: X from LDS ring, U from held reg ring ----
#define CONS(KS) do {                                                           \
    const int ko = (KS) * 64 + g16;                                             \
    bf16x8 axr = *(const bf16x8*)(xsp + aro + (ko ^ aswz));                     \
    bf16x8 axi = *(const bf16x8*)(xsp + 8192 + aro + (ko ^ aswz));              \
    bf16x8 bur = uhr, bui = uhi;                                                \
    uhr = *(const bf16x8*)(Upr + ubA + ((((KS) + 1) & 7) << 9));                \
    uhi = *(const bf16x8*)(Upi + ubA + ((((KS) + 1) & 7) << 9));                \
    bf16x8 axrn = axr ^ (short)0x8000;                                          \
    yR = mfma16(axr,  bur, yR);                                                 \
    yR = mfma16(axi,  bui, yR);                                                 \
    yI = mfma16(axi,  bur, yI);                                                 \
    yI = mfma16(axrn, bui, yI);                                                 \
} while (0)

// ---- one phase-pair (Q literal 0..7), slice-granular held buffer H ----
#define PAIR(Q) do {                                                            \
    const char* xsp = smem + ((Q) & 1) * 32768 + wj16k;                         \
    if ((Q) < 7) {   /* write H = slice A of pair Q+1 (loaded mid pair Q-1) */  \
        char* wp0 = smem + (((Q) + 1) & 1) * 32768;                             \
        *(uint2*)(wp0 + wr0o)        = cvt2(hA0);                               \
        *(uint2*)(wp0 + wr1o)        = cvt2(hA1);                               \
        *(uint2*)(wp0 + 8192 + wr0o) = cvt2(hA2);                               \
        *(uint2*)(wp0 + 8192 + wr1o) = cvt2(hA3);                               \
        TRDOT(PB((Q) + 1), hA0, hA1, hA2, hA3);                                 \
        const int r0 = (PB((Q) + 1) + 16 + sr0) * 256 + xl4;                    \
        const int r1 = (PB((Q) + 1) + 16 + sr1) * 256 + xl4;                    \
        hA0 = *(const f32x4*)(xr + xgb + r0);   /* H <- slice B of pair Q+1 */  \
        hA1 = *(const f32x4*)(xr + xgb + r1);                                   \
        hA2 = *(const f32x4*)(xi + xgb + r0);                                   \
        hA3 = *(const f32x4*)(xi + xgb + r1);                                   \
    }                                                                           \
    __builtin_amdgcn_sched_barrier(0);                                          \
    CONS(0); CONS(1); CONS(2); CONS(3);                                         \
    if ((Q) < 7) {   /* write H = slice B of pair Q+1 */                        \
        char* wp1 = smem + (((Q) + 1) & 1) * 32768 + 16384;                     \
        *(uint2*)(wp1 + wr0o)        = cvt2(hA0);                               \
        *(uint2*)(wp1 + wr1o)        = cvt2(hA1);                               \
        *(uint2*)(wp1 + 8192 + wr0o) = cvt2(hA2);                               \
        *(uint2*)(wp1 + 8192 + wr1o) = cvt2(hA3);                               \
        TRDOT(PB((Q) + 1) + 16, hA0, hA1, hA2, hA3);                            \
    }                                                                           \
    if ((Q) < 6) {   /* H <- slice A of pair Q+2 */                             \
        const int r0 = (PB((Q) + 2) + sr0) * 256 + xl4;                         \
        const int r1 = (PB((Q) + 2) + sr1) * 256 + xl4;                         \
        hA0 = *(const f32x4*)(xr + xgb + r0);                                   \
        hA1 = *(const f32x4*)(xr + xgb + r1);                                   \
        hA2 = *(const f32x4*)(xi + xgb + r0);                                   \
        hA3 = *(const f32x4*)(xi + xgb + r1);                                   \
    }                                                                           \
    __builtin_amdgcn_sched_barrier(0);                                          \
    CONS(4); CONS(5); CONS(6); CONS(7);                                         \
    {                                                                           \
        const int yw = ytw0 ^ (((Q) & 1) << 6);                                 \
        *(uint2*)(smem + 65536 + yw) = cvt2(yR);                                \
        *(uint2*)(smem + 73728 + yw) = cvt2(yI);                                \
    }                                                                           \
    yR = zero; yI = zero;                                                       \
    asm volatile("s_waitcnt lgkmcnt(0)" ::: "memory");                          \
    __builtin_amdgcn_sched_barrier(0);                                          \
    __builtin_amdgcn_s_barrier();                                               \
    __builtin_amdgcn_sched_barrier(0);                                          \
} while (0)

// ---- stage B (packed-U A-operand) ----
#define STAGEB_KS(JT, KS2) do {                                                 \
    const int s2 = (JT) * 2 + (KS2);                                            \
    bf16x8 aur0 = *(const bf16x8*)(Upr + ((wm * 2 + 0) * 8 + s2) * 512 + l8);   \
    bf16x8 aui0 = *(const bf16x8*)(Upi + ((wm * 2 + 0) * 8 + s2) * 512 + l8);   \
    bf16x8 aur1 = *(const bf16x8*)(Upr + ((wm * 2 + 1) * 8 + s2) * 512 + l8);   \
    bf16x8 aui1 = *(const bf16x8*)(Upi + ((wm * 2 + 1) * 8 + s2) * 512 + l8);   \
    bf16x8 auin0 = aui0 ^ (short)0x8000;                                        \
    bf16x8 auin1 = aui1 ^ (short)0x8000;                                        \
    {                                                                           \
        const int off = ybA + (((KS2) * 64 + g16) ^ ysA);                       \
        bf16x8 byr = *(const bf16x8*)(smem + 65536 + off);                      \
        bf16x8 byi = *(const bf16x8*)(smem + 73728 + off);                      \
        sR00 = mfma16(aur0,  byr, sR00); sR00 = mfma16(auin0, byi, sR00);       \
        sI00 = mfma16(aui0,  byr, sI00); sI00 = mfma16(aur0,  byi, sI00);       \
        sR10 = mfma16(aur1,  byr, sR10); sR10 = mfma16(auin1, byi, sR10);       \
        sI10 = mfma16(aui1,  byr, sI10); sI10 = mfma16(aur1,  byi, sI10);       \
    }                                                                           \
    {                                                                           \
        const int off = ybA + 2048 + (((KS2) * 64 + g16) ^ ysA);                \
        bf16x8 byr = *(const bf16x8*)(smem + 65536 + off);                      \
        bf16x8 byi = *(const bf16x8*)(smem + 73728 + off);                      \
        sR01 = mfma16(aur0,  byr, sR01); sR01 = mfma16(auin0, byi, sR01);       \
        sI01 = mfma16(aui0,  byr, sI01); sI01 = mfma16(aur0,  byi, sI01);       \
        sR11 = mfma16(aur1,  byr, sR11); sR11 = mfma16(auin1, byi, sR11);       \
        sI11 = mfma16(aui1,  byr, sI11); sI11 = mfma16(aur1,  byi, sI11);       \
    }                                                                           \
} while (0)

#define STAGEB_PASS(JT) do {                                                    \
    STAGEB_KS(JT, 0);                                                           \
    STAGEB_KS(JT, 1);                                                           \
    asm volatile("s_waitcnt lgkmcnt(0)" ::: "memory");                          \
    __builtin_amdgcn_sched_barrier(0);                                          \
    __builtin_amdgcn_s_barrier();      /* Yt reads done before next writes */   \
    __builtin_amdgcn_sched_barrier(0);                                          \
} while (0)

// ---- main fused kernel ----
__global__ __launch_bounds__(512, 1) void qfused(
    const float* __restrict__ xr, const float* __restrict__ xi,
    const short* __restrict__ Upr, const short* __restrict__ Upi,
    const short* __restrict__ Qrb, const short* __restrict__ Qib,
    const float* __restrict__ pv, const float* __restrict__ sv,
    float* __restrict__ out)
{
    // [0,65536): X ring (2 pair-slots x 32KB); [65536,81920): Yt (R/I).
    // 80KB exactly -> 2 blocks/CU.
    __shared__ __align__(16) char smem[81920];

    const int bx   = blockIdx.x;
    // XCD sibling pairing: batch b's two kh-blocks share bx%8 (same XCD).
    const int b    = ((bx >> 4) << 3) | (bx & 7);
    const int kh   = (bx >> 3) & 1;
    const int tid  = threadIdx.x;
    const int lane = tid & 63;
    const int w    = tid >> 6;
    const int c16  = lane & 15;
    const int g4   = lane >> 4;
    const int g8   = g4 * 8;
    const int g16  = g4 * 16;
    const int l8   = lane * 8;

    const int wj    = w >> 2;            // my slice within pair (0/1)
    const int wk    = w & 3;             // my k'-group
    const int wj16k = wj * 16384;
    const int wm    = w >> 1;            // stage-B row-quarter
    const int wn    = w & 1;             // stage-B k'-half-of-half

    // X staging: wave stages slot-rows {w*2, w*2+1}; lane covers bytes l*16.
    const int sr0 = w * 2, sr1 = w * 2 + 1;
    const int xl4 = lane * 4;            // float offset within row
    const int xgb = b << 16;
    const int wr0o = sr0 * 512 + ((((lane >> 1) << 4) ^ ((sr0 & 7) << 4))) + ((lane & 1) << 3);
    const int wr1o = sr1 * 512 + ((((lane >> 1) << 4) ^ ((sr1 & 7) << 4))) + ((lane & 1) << 3);

    // consume: A from X-slot row c16; U-frag base for my (kh, wk) group
    const int aro  = c16 * 512;
    const int aswz = (c16 & 7) << 4;
    const int ubA  = (kh * 4 + wk) * 4096 + l8;   // shorts: ((g*8+s)*64+lane)*8

    // Yt write offset (pair-parity toggles bit 6)
    const int ukl  = wk * 16 + c16;
    const int ytw0 = ukl * 128 + ((wj * 32 + g8) ^ ((ukl & 7) << 4));

    // stage-B Yt read offsets
    const int ybA = (wn * 32 + c16) * 128;
    const int ysA = ((wn * 32 + c16) & 7) << 4;

    f32x4 zero = {0.f, 0.f, 0.f, 0.f};
    f32x4 sR00 = zero, sR01 = zero, sR10 = zero, sR11 = zero;
    f32x4 sI00 = zero, sI01 = zero, sI10 = zero, sI11 = zero;
    float tracc = 0.f;
    f32x4 yR = zero, yI = zero;
    f32x4 hA0, hA1, hA2, hA3;            // held X slice buffer (16 regs)
    bf16x8 uhr, uhi;                     // held U fragment ring (8 regs)

    // ---- prologue: direct-stage pair 0 (+TRDOT); H <- pair-1 slice A;
    //      prime U ring (ks=0) ----
    {
        const int r0 = (PB(0) + sr0) * 256 + xl4;
        const int r1 = (PB(0) + sr1) * 256 + xl4;
        const int r2 = (PB(0) + 16 + sr0) * 256 + xl4;
        const int r3 = (PB(0) + 16 + sr1) * 256 + xl4;
        f32x4 a0 = *(const f32x4*)(xr + xgb + r0);
        f32x4 a1 = *(const f32x4*)(xr + xgb + r1);
        f32x4 a2 = *(const f32x4*)(xi + xgb + r0);
        f32x4 a3 = *(const f32x4*)(xi + xgb + r1);
        f32x4 b0 = *(const f32x4*)(xr + xgb + r2);
        f32x4 b1 = *(const f32x4*)(xr + xgb + r3);
        f32x4 b2 = *(const f32x4*)(xi + xgb + r2);
        f32x4 b3 = *(const f32x4*)(xi + xgb + r3);
        const int r4 = (PB(1) + sr0) * 256 + xl4;
        const int r5 = (PB(1) + sr1) * 256 + xl4;
        hA0 = *(const f32x4*)(xr + xgb + r4);
        hA1 = *(const f32x4*)(xr + xgb + r5);
        hA2 = *(const f32x4*)(xi + xgb + r4);
        hA3 = *(const f32x4*)(xi + xgb + r5);
        uhr = *(const bf16x8*)(Upr + ubA);
        uhi = *(const bf16x8*)(Upi + ubA);
        char* w0p = smem;
        char* w1p = smem + 16384;
        *(uint2*)(w0p + wr0o)        = cvt2(a0);
        *(uint2*)(w0p + wr1o)        = cvt2(a1);
        *(uint2*)(w0p + 8192 + wr0o) = cvt2(a2);
        *(uint2*)(w0p + 8192 + wr1o) = cvt2(a3);
        *(uint2*)(w1p + wr0o)        = cvt2(b0);
        *(uint2*)(w1p + wr1o)        = cvt2(b1);
        *(uint2*)(w1p + 8192 + wr0o) = cvt2(b2);
        *(uint2*)(w1p + 8192 + wr1o) = cvt2(b3);
        TRDOT(PB(0),      a0, a1, a2, a3);
        TRDOT(PB(0) + 16, b0, b1, b2, b3);
    }
    asm volatile("s_waitcnt lgkmcnt(0)" ::: "memory");
    __builtin_amdgcn_sched_barrier(0);
    __builtin_amdgcn_s_barrier();
    __builtin_amdgcn_sched_barrier(0);

    PAIR(0);
    PAIR(1);
    STAGEB_PASS(0);
    PAIR(2);
    PAIR(3);
    STAGEB_PASS(1);
    PAIR(4);
    PAIR(5);
    STAGEB_PASS(2);
    PAIR(6);
    PAIR(7);
    STAGEB_KS(3, 0);
    STAGEB_KS(3, 1);

    // ---- trace reduce ----
    float loc = tracc;
    #pragma unroll
    for (int o = 32; o > 0; o >>= 1) loc += __shfl_xor(loc, o);
    __syncthreads();                      // loop LDS traffic done
    float* red = (float*)(smem + 65536);
    if (lane == 0) red[w] = loc;
    __syncthreads();
    float tr = red[0] + red[1] + red[2] + red[3] +
               red[4] + red[5] + red[6] + red[7];

    float s     = sv[0];
    float inv   = s / tr;
    float onems = 1.f - s;
    float* outr = out + (size_t)b * 16384;
    float* outi = out + 8388608 + (size_t)b * 16384;

    #define EPI(SRV, SIV, MT, NT) do {                                          \
        int colc = kh * 64 + wn * 32 + (NT) * 16 + c16;                         \
        _Pragma("unroll")                                                       \
        for (int r = 0; r < 4; ++r) {                                           \
            int row = wm * 32 + (MT) * 16 + g4 * 4 + r;                         \
            float vr = SRV[r] * inv;                                            \
            if (row == colc) vr += onems * pv[row];                             \
            outr[row * 128 + colc] = vr;                                        \
            outi[row * 128 + colc] = SIV[r] * inv;                              \
        }                                                                       \
    } while (0)

    EPI(sR00, sI00, 0, 0);
    EPI(sR01, sI01, 0, 1);
    EPI(sR10, sI10, 1, 0);
    EPI(sR11, sI11, 1, 1);
    #undef EPI
}

extern "C" void kernel_launch(void* const* d_in, const int* in_sizes, int n_in,
                              void* d_out, int out_size, void* d_ws, size_t ws_size,
                              hipStream_t stream) {
    (void)in_sizes; (void)n_in; (void)out_size; (void)ws_size;
    const float* xr = (const float*)d_in[0];
    const float* xi = (const float*)d_in[1];
    const float* wt = (const float*)d_in[2];
    const float* rw = (const float*)d_in[3];
    const float* lm = (const float*)d_in[4];

    short* Upr = (short*)d_ws;                        // 64 KB packed frags
    short* Upi = (short*)((char*)d_ws + 65536);       // 64 KB
    short* Qrb = (short*)((char*)d_ws + 131072);      // 128 KB row-major bf16
    short* Qib = (short*)((char*)d_ws + 262144);      // 128 KB
    float* pv  = (float*)((char*)d_ws + 393216);      // 128 f32
    float* sv  = pv + 128;                            // 1 f32
    float* o   = (float*)d_out;

    qprep_u<<<dim3(128), dim3(256), 0, stream>>>(wt, Upr, Upi);
    qprep_ps<<<dim3(1), dim3(64), 0, stream>>>(rw, lm, pv, sv);
    qprep_q<<<dim3(256), dim3(256), 0, stream>>>(wt, Qrb, Qib);
    qfused<<<dim3(1024), dim3(512), 0, stream>>>(xr, xi, Upr, Upi,
                                                 Qrb, Qib, pv, sv, o);
}

// Round 20
// 147.081 us; speedup vs baseline: 1.1220x; 1.1220x over previous
//
#include <hip/hip_runtime.h>
#include <hip/hip_bf16.h>

// QDense: out = s * (U X U^H)[:128,:128] / tr + (1-s) * diag(softmax(rand_w))
// B=512, D=256, O=128.
// FINAL = round-17 restored verbatim (best measured: 149.2us).
// Session ledger: r18 (+8 held-Q regs) and r19 (U->global reg-ring) both
// regressed; the 128-VGPR allocator wall + ~52 accumulator AGPRs (unified
// file) make every added pipeline register spill, and every LDS-operand
// removal adds a serial VMEM chain.  r17 is the empirical optimum of this
// structure family:
//   - full-row 1KB coalesced X loads, f32->bf16 (v_cvt_pk) at staging
//   - 4-slot (2-pair) LDS X ring, XOR-swizzled, 1 barrier/pair, lgkmcnt-only
//     (vmcnt stays counted across barriers)
//   - slice-granular 16-reg held prefetch H (~1 pair of HBM-latency cover)
//   - XCD sibling pairing: (b,kh=0/1) share bx%8 -> sibling X reads hit L2
//     (FETCH 297->148MB measured)
//   - U-half swizzled in LDS (stage A), fragment-packed U in global (stage B)
//   - trace = elementwise VALU dot on staging registers vs Q=(U^H U)^T
// LDS: U 64K + Yt 16K + X-ring 64K = 144KB -> 1 block/CU.  1024 blocks, 512 thr.

typedef __attribute__((ext_vector_type(4))) float f32x4;
typedef __attribute__((ext_vector_type(8))) short bf16x8;

static __device__ __forceinline__ short f2bf(float f) {   // prep kernels only
    unsigned u = __float_as_uint(f);
    u += 0x7fffu + ((u >> 16) & 1u);
    return (short)(u >> 16);
}

static __device__ __forceinline__ float b2f(unsigned short h) {
    return __uint_as_float(((unsigned)h) << 16);
}

static __device__ __forceinline__ unsigned cvtpk2(float lo, float hi) {
    union { __hip_bfloat162 h; unsigned u; } c;
    c.h = __float22bfloat162_rn(float2{lo, hi});
    return c.u;
}

static __device__ __forceinline__ uint2 cvt2(f32x4 v) {
    uint2 r;
    r.x = cvtpk2(v[0], v[1]);
    r.y = cvtpk2(v[2], v[3]);
    return r;
}

static __device__ __forceinline__ f32x4 mfma16(bf16x8 a, bf16x8 b, f32x4 c) {
    return __builtin_amdgcn_mfma_f32_16x16x32_bf16(a, b, c, 0, 0, 0);
}

// ---- prep: U -> bf16 row-major (Ur/Ui) and fragment-packed (Upr/Upi) ----
__global__ void qprep_u(const float* __restrict__ wt,
                        short* __restrict__ Ur,  short* __restrict__ Ui,
                        short* __restrict__ Upr, short* __restrict__ Upi) {
    int idx = blockIdx.x * 256 + threadIdx.x;     // j*256+k, j<128
    int j = idx >> 8, k = idx & 255;
    float2 v = ((const float2*)wt)[idx];
    short br = f2bf(v.x), bi = f2bf(v.y);
    Ur[idx] = br;
    Ui[idx] = bi;
    int g = j >> 4, s = k >> 5;
    int lanep = (j & 15) | (((k >> 3) & 3) << 4);
    int p = ((g * 8 + s) * 64 + lanep) * 8 + (k & 7);
    Upr[p] = br;
    Upi[p] = bi;
}

__global__ void qprep_ps(const float* __restrict__ rw, const float* __restrict__ lm,
                         float* __restrict__ pv, float* __restrict__ sv) {
    int t = threadIdx.x;
    float w0 = rw[t], w1 = rw[t + 64];
    float m = fmaxf(w0, w1);
    #pragma unroll
    for (int o = 32; o > 0; o >>= 1) m = fmaxf(m, __shfl_xor(m, o));
    float e0 = expf(w0 - m), e1 = expf(w1 - m);
    float ss = e0 + e1;
    #pragma unroll
    for (int o = 32; o > 0; o >>= 1) ss += __shfl_xor(ss, o);
    pv[t] = e0 / ss;
    pv[t + 64] = e1 / ss;
    if (t == 0) sv[0] = 1.f / (1.f + expf(-lm[0]));
}

// Q[j][k] = P[k][j], P = U_sub^H U_sub  (bf16, row-major)
__global__ void qprep_q(const float* __restrict__ wt,
                        short* __restrict__ Qrb, short* __restrict__ Qib) {
    int j = blockIdx.x;
    int k = threadIdx.x;
    float ar = 0.f, ai = 0.f;
    for (int i = 0; i < 128; ++i) {
        float2 uk = ((const float2*)wt)[i * 256 + k];
        float2 uj = ((const float2*)wt)[i * 256 + j];
        ar += uk.x * uj.x + uk.y * uj.y;
        ai += uk.x * uj.y - uk.y * uj.x;
    }
    Qrb[j * 256 + k] = f2bf(ar);
    Qib[j * 256 + k] = f2bf(ai);
}

#define PB(Q) ((Q) * 32)                 // pair row base (rows in batch)

// ---- elementwise trace dot on held regs (rows RB+sr0, RB+sr1) ----
#define TRDOT(RB, A0, A1, A2, A3) do {                                          \
    const int qo0 = ((RB) + sr0) * 256 + xl4;                                   \
    const int qo1 = ((RB) + sr1) * 256 + xl4;                                   \
    ushort4 hr0 = *(const ushort4*)(Qrb + qo0);                                 \
    ushort4 hr1 = *(const ushort4*)(Qrb + qo1);                                 \
    ushort4 hi0 = *(const ushort4*)(Qib + qo0);                                 \
    ushort4 hi1 = *(const ushort4*)(Qib + qo1);                                 \
    tracc += A0[0]*b2f(hr0.x) + A0[1]*b2f(hr0.y)                                \
           + A0[2]*b2f(hr0.z) + A0[3]*b2f(hr0.w);                               \
    tracc += A1[0]*b2f(hr1.x) + A1[1]*b2f(hr1.y)                                \
           + A1[2]*b2f(hr1.z) + A1[3]*b2f(hr1.w);                               \
    tracc -= A2[0]*b2f(hi0.x) + A2[1]*b2f(hi0.y)                                \
           + A2[2]*b2f(hi0.z) + A2[3]*b2f(hi0.w);                               \
    tracc -= A3[0]*b2f(hi1.x) + A3[1]*b2f(hi1.y)                                \
           + A3[2]*b2f(hi1.z) + A3[3]*b2f(hi1.w);                               \
} while (0)

// ---- consume one ks step ----
#define CONS(KS) do {                                                           \
    const int ko = (KS) * 64 + g16;                                             \
    bf16x8 axr = *(const bf16x8*)(xsp + aro + (ko ^ aswz));                     \
    bf16x8 axi = *(const bf16x8*)(xsp + 8192 + aro + (ko ^ aswz));              \
    bf16x8 bur = *(const bf16x8*)(smem + uob + (ko ^ uswz));                    \
    bf16x8 bui = *(const bf16x8*)(smem + 32768 + uob + (ko ^ uswz));            \
    bf16x8 axrn = axr ^ (short)0x8000;                                          \
    yR = mfma16(axr,  bur, yR);                                                 \
    yR = mfma16(axi,  bui, yR);                                                 \
    yI = mfma16(axi,  bur, yI);                                                 \
    yI = mfma16(axrn, bui, yI);                                                 \
} while (0)

// ---- one phase-pair (Q literal 0..7), slice-granular held buffer H ----
#define PAIR(Q) do {                                                            \
    const char* xsp = smem + 81920 + ((Q) & 1) * 32768 + wj16k;                 \
    if ((Q) < 7) {   /* write H = slice A of pair Q+1 (issued mid pair Q-1) */  \
        char* wp0 = smem + 81920 + (((Q) + 1) & 1) * 32768;                     \
        *(uint2*)(wp0 + wr0o)        = cvt2(hA0);                               \
        *(uint2*)(wp0 + wr1o)        = cvt2(hA1);                               \
        *(uint2*)(wp0 + 8192 + wr0o) = cvt2(hA2);                               \
        *(uint2*)(wp0 + 8192 + wr1o) = cvt2(hA3);                               \
        TRDOT(PB((Q) + 1), hA0, hA1, hA2, hA3);                                 \
        const int r0 = (PB((Q) + 1) + 16 + sr0) * 256 + xl4;                    \
        const int r1 = (PB((Q) + 1) + 16 + sr1) * 256 + xl4;                    \
        hA0 = *(const f32x4*)(xr + xgb + r0);   /* H <- slice B of pair Q+1 */  \
        hA1 = *(const f32x4*)(xr + xgb + r1);                                   \
        hA2 = *(const f32x4*)(xi + xgb + r0);                                   \
        hA3 = *(const f32x4*)(xi + xgb + r1);                                   \
    }                                                                           \
    __builtin_amdgcn_sched_barrier(0);                                          \
    CONS(0); CONS(1); CONS(2); CONS(3);                                         \
    if ((Q) < 7) {   /* write H = slice B of pair Q+1 */                        \
        char* wp1 = smem + 81920 + (((Q) + 1) & 1) * 32768 + 16384;             \
        *(uint2*)(wp1 + wr0o)        = cvt2(hA0);                               \
        *(uint2*)(wp1 + wr1o)        = cvt2(hA1);                               \
        *(uint2*)(wp1 + 8192 + wr0o) = cvt2(hA2);                               \
        *(uint2*)(wp1 + 8192 + wr1o) = cvt2(hA3);                               \
        TRDOT(PB((Q) + 1) + 16, hA0, hA1, hA2, hA3);                            \
    }                                                                           \
    if ((Q) < 6) {   /* H <- slice A of pair Q+2 */                             \
        const int r0 = (PB((Q) + 2) + sr0) * 256 + xl4;                         \
        const int r1 = (PB((Q) + 2) + sr1) * 256 + xl4;                         \
        hA0 = *(const f32x4*)(xr + xgb + r0);                                   \
        hA1 = *(const f32x4*)(xr + xgb + r1);                                   \
        hA2 = *(const f32x4*)(xi + xgb + r0);                                   \
        hA3 = *(const f32x4*)(xi + xgb + r1);                                   \
    }                                                                           \
    __builtin_amdgcn_sched_barrier(0);                                          \
    CONS(4); CONS(5); CONS(6); CONS(7);                                         \
    {                                                                           \
        const int yw = ((Q) & 1) ? ytw1 : ytw0;                                 \
        *(uint2*)(smem + 65536 + yw) = cvt2(yR);                                \
        *(uint2*)(smem + 73728 + yw) = cvt2(yI);                                \
    }                                                                           \
    yR = zero; yI = zero;                                                       \
    asm volatile("s_waitcnt lgkmcnt(0)" ::: "memory");                          \
    __builtin_amdgcn_sched_barrier(0);                                          \
    __builtin_amdgcn_s_barrier();                                               \
    __builtin_amdgcn_sched_barrier(0);                                          \
} while (0)

// ---- stage B (packed-U A-operand) ----
#define STAGEB_KS(JT, KS2) do {                                                 \
    const int s2 = (JT) * 2 + (KS2);                                            \
    bf16x8 aur0 = *(const bf16x8*)(Upr + ((wm * 2 + 0) * 8 + s2) * 512 + l8);   \
    bf16x8 aui0 = *(const bf16x8*)(Upi + ((wm * 2 + 0) * 8 + s2) * 512 + l8);   \
    bf16x8 aur1 = *(const bf16x8*)(Upr + ((wm * 2 + 1) * 8 + s2) * 512 + l8);   \
    bf16x8 aui1 = *(const bf16x8*)(Upi + ((wm * 2 + 1) * 8 + s2) * 512 + l8);   \
    bf16x8 auin0 = aui0 ^ (short)0x8000;                                        \
    bf16x8 auin1 = aui1 ^ (short)0x8000;                                        \
    {                                                                           \
        const int off = ybA + (((KS2) * 64 + g16) ^ ysA);                       \
        bf16x8 byr = *(const bf16x8*)(smem + 65536 + off);                      \
        bf16x8 byi = *(const bf16x8*)(smem + 73728 + off);                      \
        sR00 = mfma16(aur0,  byr, sR00); sR00 = mfma16(auin0, byi, sR00);       \
        sI00 = mfma16(aui0,  byr, sI00); sI00 = mfma16(aur0,  byi, sI00);       \
        sR10 = mfma16(aur1,  byr, sR10); sR10 = mfma16(auin1, byi, sR10);       \
        sI10 = mfma16(aui1,  byr, sI10); sI10 = mfma16(aur1,  byi, sI10);       \
    }                                                                           \
    {                                                                           \
        const int off = ybB + (((KS2) * 64 + g16) ^ ysB);                       \
        bf16x8 byr = *(const bf16x8*)(smem + 65536 + off);                      \
        bf16x8 byi = *(const bf16x8*)(smem + 73728 + off);                      \
        sR01 = mfma16(aur0,  byr, sR01); sR01 = mfma16(auin0, byi, sR01);       \
        sI01 = mfma16(aui0,  byr, sI01); sI01 = mfma16(aur0,  byi, sI01);       \
        sR11 = mfma16(aur1,  byr, sR11); sR11 = mfma16(auin1, byi, sR11);       \
        sI11 = mfma16(aui1,  byr, sI11); sI11 = mfma16(aur1,  byi, sI11);       \
    }                                                                           \
} while (0)

#define STAGEB_PASS(JT) do {                                                    \
    STAGEB_KS(JT, 0);                                                           \
    STAGEB_KS(JT, 1);                                                           \
    asm volatile("s_waitcnt lgkmcnt(0)" ::: "memory");                          \
    __builtin_amdgcn_sched_barrier(0);                                          \
    __builtin_amdgcn_s_barrier();      /* Yt reads done before next writes */   \
    __builtin_amdgcn_sched_barrier(0);                                          \
} while (0)

// ---- main fused kernel ----
__global__ __launch_bounds__(512, 1) void qfused(
    const float* __restrict__ xr, const float* __restrict__ xi,
    const short* __restrict__ Urg, const short* __restrict__ Uig,
    const short* __restrict__ Upr, const short* __restrict__ Upi,
    const short* __restrict__ Qrb, const short* __restrict__ Qib,
    const float* __restrict__ pv, const float* __restrict__ sv,
    float* __restrict__ out)
{
    // [0,65536) U-half swizzled (R 0, I 32768); [65536,81920) Yt (R/I);
    // [81920,147456) X ring: 2 pair-slots x (sliceA 16KB + sliceB 16KB).
    __shared__ __align__(16) char smem[147456];

    const int bx   = blockIdx.x;
    // XCD sibling pairing: batch b's two kh-blocks share bx%8 (same XCD).
    const int b    = ((bx >> 4) << 3) | (bx & 7);
    const int kh   = (bx >> 3) & 1;
    const int tid  = threadIdx.x;
    const int lane = tid & 63;
    const int w    = tid >> 6;
    const int c16  = lane & 15;
    const int g4   = lane >> 4;
    const int g8   = g4 * 8;
    const int g16  = g4 * 16;
    const int l8   = lane * 8;

    const int wj    = w >> 2;            // my slice within pair (0/1)
    const int wk    = w & 3;             // my k'-group
    const int wj16k = wj * 16384;
    const int wm    = w >> 1;            // stage-B row-quarter
    const int wn    = w & 1;             // stage-B k'-half-of-half

    // X staging: wave stages slot-rows {w*2, w*2+1}; lane covers bytes l*16.
    const int sr0 = w * 2, sr1 = w * 2 + 1;
    const int xl4 = lane * 4;            // float offset within row
    const int xgb = b << 16;
    const int wr0o = sr0 * 512 + ((((lane >> 1) << 4) ^ ((sr0 & 7) << 4))) + ((lane & 1) << 3);
    const int wr1o = sr1 * 512 + ((((lane >> 1) << 4) ^ ((sr1 & 7) << 4))) + ((lane & 1) << 3);

    // consume: A from X-slot row c16; B from U-LDS row wk*16+c16
    const int aro  = c16 * 512;
    const int aswz = (c16 & 7) << 4;
    const int ukl  = wk * 16 + c16;
    const int uob  = ukl * 512;
    const int uswz = (ukl & 7) << 4;

    // Yt write offsets (pair 0 / pair 1 within a pass)
    const int ytr  = ukl;
    const int ytk  = (ytr & 7) << 4;
    const int ytw0 = ytr * 128 + ((wj * 32 + g8) ^ ytk);
    const int ytw1 = ytr * 128 + ((64 + wj * 32 + g8) ^ ytk);

    // stage-B Yt read offsets
    const int ybA = (wn * 32 + c16) * 128;
    const int ybB = (wn * 32 + 16 + c16) * 128;
    const int ysA = ((wn * 32 + c16) & 7) << 4;
    const int ysB = ((wn * 32 + 16 + c16) & 7) << 4;

    // ---- stage U-half into swizzled LDS (r3-proven) ----
    #pragma unroll
    for (int q = 0; q < 4; ++q) {
        int c    = tid + q * 512;
        int row  = c >> 5;
        int slot = c & 31;
        int ss   = slot ^ (row & 7);
        const short* sr = Urg + (size_t)(kh * 64 + row) * 256 + ss * 8;
        const short* si = Uig + (size_t)(kh * 64 + row) * 256 + ss * 8;
        *(bf16x8*)(smem + row * 512 + slot * 16)         = *(const bf16x8*)sr;
        *(bf16x8*)(smem + 32768 + row * 512 + slot * 16) = *(const bf16x8*)si;
    }

    f32x4 zero = {0.f, 0.f, 0.f, 0.f};
    f32x4 sR00 = zero, sR01 = zero, sR10 = zero, sR11 = zero;
    f32x4 sI00 = zero, sI01 = zero, sI10 = zero, sI11 = zero;
    float tracc = 0.f;
    f32x4 yR = zero, yI = zero;
    f32x4 hA0, hA1, hA2, hA3;            // single 16-reg held slice buffer

    // ---- prologue: direct-stage pair 0 (+TRDOT); H <- pair-1 slice A ----
    {
        const int r0 = (PB(0) + sr0) * 256 + xl4;
        const int r1 = (PB(0) + sr1) * 256 + xl4;
        const int r2 = (PB(0) + 16 + sr0) * 256 + xl4;
        const int r3 = (PB(0) + 16 + sr1) * 256 + xl4;
        f32x4 a0 = *(const f32x4*)(xr + xgb + r0);
        f32x4 a1 = *(const f32x4*)(xr + xgb + r1);
        f32x4 a2 = *(const f32x4*)(xi + xgb + r0);
        f32x4 a3 = *(const f32x4*)(xi + xgb + r1);
        f32x4 b0 = *(const f32x4*)(xr + xgb + r2);
        f32x4 b1 = *(const f32x4*)(xr + xgb + r3);
        f32x4 b2 = *(const f32x4*)(xi + xgb + r2);
        f32x4 b3 = *(const f32x4*)(xi + xgb + r3);
        const int r4 = (PB(1) + sr0) * 256 + xl4;
        const int r5 = (PB(1) + sr1) * 256 + xl4;
        hA0 = *(const f32x4*)(xr + xgb + r4);
        hA1 = *(const f32x4*)(xr + xgb + r5);
        hA2 = *(const f32x4*)(xi + xgb + r4);
        hA3 = *(const f32x4*)(xi + xgb + r5);
        char* w0p = smem + 81920;
        char* w1p = smem + 81920 + 16384;
        *(uint2*)(w0p + wr0o)        = cvt2(a0);
        *(uint2*)(w0p + wr1o)        = cvt2(a1);
        *(uint2*)(w0p + 8192 + wr0o) = cvt2(a2);
        *(uint2*)(w0p + 8192 + wr1o) = cvt2(a3);
        *(uint2*)(w1p + wr0o)        = cvt2(b0);
        *(uint2*)(w1p + wr1o)        = cvt2(b1);
        *(uint2*)(w1p + 8192 + wr0o) = cvt2(b2);
        *(uint2*)(w1p + 8192 + wr1o) = cvt2(b3);
        TRDOT(PB(0),      a0, a1, a2, a3);
        TRDOT(PB(0) + 16, b0, b1, b2, b3);
    }
    asm volatile("s_waitcnt lgkmcnt(0)" ::: "memory");
    __builtin_amdgcn_sched_barrier(0);
    __builtin_amdgcn_s_barrier();
    __builtin_amdgcn_sched_barrier(0);

    PAIR(0);
    PAIR(1);
    STAGEB_PASS(0);
    PAIR(2);
    PAIR(3);
    STAGEB_PASS(1);
    PAIR(4);
    PAIR(5);
    STAGEB_PASS(2);
    PAIR(6);
    PAIR(7);
    STAGEB_KS(3, 0);
    STAGEB_KS(3, 1);

    // ---- trace: elementwise dot summed over all lanes/waves ----
    float loc = tracc;
    #pragma unroll
    for (int o = 32; o > 0; o >>= 1) loc += __shfl_xor(loc, o);
    __syncthreads();                      // Yt dead; reuse for reduction
    float* red = (float*)(smem + 65536);
    if (lane == 0) red[w] = loc;
    __syncthreads();
    float tr = red[0] + red[1] + red[2] + red[3] +
               red[4] + red[5] + red[6] + red[7];

    float s     = sv[0];
    float inv   = s / tr;
    float onems = 1.f - s;
    float* outr = out + (size_t)b * 16384;
    float* outi = out + 8388608 + (size_t)b * 16384;

    #define EPI(SRV, SIV, MT, NT) do {                                          \
        int colc = kh * 64 + wn * 32 + (NT) * 16 + c16;                         \
        _Pragma("unroll")                                                       \
        for (int r = 0; r < 4; ++r) {                                           \
            int row = wm * 32 + (MT) * 16 + g4 * 4 + r;                         \
            float vr = SRV[r] * inv;                                            \
            if (row == colc) vr += onems * pv[row];                             \
            outr[row * 128 + colc] = vr;                                        \
            outi[row * 128 + colc] = SIV[r] * inv;                              \
        }                                                                       \
    } while (0)

    EPI(sR00, sI00, 0, 0);
    EPI(sR01, sI01, 0, 1);
    EPI(sR10, sI10, 1, 0);
    EPI(sR11, sI11, 1, 1);
    #undef EPI
}

extern "C" void kernel_launch(void* const* d_in, const int* in_sizes, int n_in,
                              void* d_out, int out_size, void* d_ws, size_t ws_size,
                              hipStream_t stream) {
    (void)in_sizes; (void)n_in; (void)out_size; (void)ws_size;
    const float* xr = (const float*)d_in[0];
    const float* xi = (const float*)d_in[1];
    const float* wt = (const float*)d_in[2];
    const float* rw = (const float*)d_in[3];
    const float* lm = (const float*)d_in[4];

    short* Ur  = (short*)d_ws;                        // 64 KB row-major bf16
    short* Ui  = (short*)((char*)d_ws + 65536);       // 64 KB
    short* Upr = (short*)((char*)d_ws + 131072);      // 64 KB packed frags
    short* Upi = (short*)((char*)d_ws + 196608);      // 64 KB
    short* Qrb = (short*)((char*)d_ws + 262144);      // 128 KB row-major bf16
    short* Qib = (short*)((char*)d_ws + 393216);      // 128 KB
    float* pv  = (float*)((char*)d_ws + 524288);      // 128 f32
    float* sv  = pv + 128;                            // 1 f32
    float* o   = (float*)d_out;

    qprep_u<<<dim3(128), dim3(256), 0, stream>>>(wt, Ur, Ui, Upr, Upi);
    qprep_ps<<<dim3(1), dim3(64), 0, stream>>>(rw, lm, pv, sv);
    qprep_q<<<dim3(256), dim3(256), 0, stream>>>(wt, Qrb, Qib);
    qfused<<<dim3(1024), dim3(512), 0, stream>>>(xr, xi, Ur, Ui, Upr, Upi,
                                                 Qrb, Qib, pv, sv, o);
}